// Round 2
// baseline (252.009 us; speedup 1.0000x reference)
//
#include <hip/hip_runtime.h>
#include <hip/hip_cooperative_groups.h>

namespace cg = cooperative_groups;

// (B,N,D,L) = (32,1000,256,3), all fp32.
// d_in: [0]=x (unused), [1]=node_feature, [2]=Ws (L,D,D), [3]=bs (L,D).
// Math collapses (A_norm = ones/N):
//   h[b,:] = MLP(mean_n nf[b,n,:]);  out0 = nf + h (broadcast);  out1 = nf.
//
// R7 post-mortem: 3-launch version regressed (noise + launch gaps). The only
// controllable terms left are dispatch count and nf re-reads. R8: ONE
// cooperative dispatch; nf read from HBM exactly once and held in registers
// across the grid syncs; out1 written in phase A, out0 in phase C, MLP on 32
// blocks in phase B between two grid syncs.
#define BB 32
#define NN 1000
#define DD 256
#define SP 8                               // phase-A blocks per batch
#define CHUNK_ROWS (NN / SP)               // 125 rows per block
#define CHUNK_F4 (CHUNK_ROWS * DD / 4)     // 8000 float4 per block
#define ELEMS (BB * NN * DD)               // 8,192,000 floats per output

__global__ __launch_bounds__(1024) void k_fused(const float4* __restrict__ nf4,
                                                const float* __restrict__ Ws,
                                                const float* __restrict__ bsv,
                                                float4* __restrict__ out0_4,
                                                float4* __restrict__ out1_4,
                                                float* __restrict__ partials,
                                                float* __restrict__ hrow) {
    const int bid = blockIdx.x, t = threadIdx.x;
    const int b = bid >> 3, s = bid & (SP - 1);
    const int base = (b * NN + s * CHUNK_ROWS) * (DD / 4);
    const int c = t & 63;                  // f4-column, constant per thread
                                           // (1024 % 64 == 0 keeps it fixed)
    __shared__ float redA[4096];           // 16 KB: phase-A 16-way row reduce
    __shared__ float red[1024];            // 4 KB: phase-B k-group reduce
    __shared__ float h[DD];

    // ---- Phase A: out1 = nf (same pass), partial column sums, nf -> regs ----
    float4 vv[8];                          // statically indexed (unrolled)
    float4 acc = make_float4(0.f, 0.f, 0.f, 0.f);
#pragma unroll
    for (int k = 0; k < 8; k++) {
        const int f4o = t + k * 1024;      // wave-uniform tail (832 = 13*64)
        if (f4o < CHUNK_F4) {
            float4 v = nf4[base + f4o];
            vv[k] = v;
            out1_4[base + f4o] = v;
            acc.x += v.x; acc.y += v.y; acc.z += v.z; acc.w += v.w;
        }
    }
    ((float4*)redA)[(t >> 6) * 64 + c] = acc;   // redA[rg*256 + c*4 + j]
    __syncthreads();
    if (t < DD) {
        float sum = 0.f;
#pragma unroll
        for (int r = 0; r < 16; r++) sum += redA[r * DD + t];
        partials[(b * SP + s) * DD + t] = sum;  // no atomics, no pre-zero
    }

    cg::this_grid().sync();                // partials visible device-wide

    // ---- Phase B: whole MLP, 32 blocks (b = bid), 4 kq x 256 d ----
    if (bid < BB) {
        const int d = t & (DD - 1), kq = t >> 8;
        float pa = partials[(bid * SP + kq) * DD + d]
                 + partials[(bid * SP + kq + 4) * DD + d];
        red[t] = pa;
        __syncthreads();
        if (kq == 0)
            h[d] = (red[d] + red[DD + d] + red[2 * DD + d] + red[3 * DD + d])
                   * (1.0f / (float)NN);
        __syncthreads();
        for (int l = 0; l < 3; l++) {
            const float* __restrict__ W = Ws + l * DD * DD;
            float a = 0.f;
#pragma unroll
            for (int kk = 0; kk < 64; kk++) {
                const int k = kq * 64 + kk;
                a += h[k] * W[k * DD + d];  // lanes span d: coalesced, L2-hot
            }
            __syncthreads();               // all h reads done before overwrite
            red[t] = a;
            __syncthreads();               // red visible
            if (kq == 0) {
                float o = red[d] + red[DD + d] + red[2 * DD + d] + red[3 * DD + d]
                          + bsv[l * DD + d];
                if (l < 2) o = fmaxf(o, 0.f);
                if (l == 2) hrow[bid * DD + d] = o;
                else        h[d] = o;
            }
            __syncthreads();               // h visible before next layer
        }
    }

    cg::this_grid().sync();                // hrow visible device-wide

    // ---- Phase C: out0 = regs + h[b]; zero nf re-read ----
    const float4 hv = *(const float4*)(hrow + b * DD + c * 4);
#pragma unroll
    for (int k = 0; k < 8; k++) {
        const int f4o = t + k * 1024;
        if (f4o < CHUNK_F4) {
            float4 v = vv[k];
            out0_4[base + f4o] = make_float4(v.x + hv.x, v.y + hv.y,
                                             v.z + hv.z, v.w + hv.w);
        }
    }
}

extern "C" void kernel_launch(void* const* d_in, const int* in_sizes, int n_in,
                              void* d_out, int out_size, void* d_ws, size_t ws_size,
                              hipStream_t stream) {
    const float4* nf4 = (const float4*)d_in[1];  // node_feature
    const float* Ws   = (const float*)d_in[2];   // (L,D,D)
    const float* bsv  = (const float*)d_in[3];   // (L,D)
    float4* out0 = (float4*)d_out;
    float4* out1 = (float4*)((float*)d_out + ELEMS);

    float* partials = (float*)d_ws;              // BB*SP*DD floats (256 KB)
    float* hrow     = partials + BB * SP * DD;   // BB*DD floats

    void* args[] = {(void*)&nf4, (void*)&Ws, (void*)&bsv, (void*)&out0,
                    (void*)&out1, (void*)&partials, (void*)&hrow};
    hipLaunchCooperativeKernel(k_fused, dim3(BB * SP), dim3(1024),
                               args, 0u, stream);
}